// Round 10
// baseline (388.315 us; speedup 1.0000x reference)
//
#include <hip/hip_runtime.h>
#include <math.h>

namespace {
constexpr int   NB   = 25;     // basis functions
constexpr int   TS   = 301;    // time steps
constexpr int   TPAD = 304;    // padded table stride
constexpr float DT   = 0.01f;
constexpr float TAU  = 3.0f;
constexpr float AX   = 2.0f;
constexpr float AZ   = 48.0f;
constexpr float BZ   = 12.0f;  // AZ/4
constexpr int   ROWS = 131072; // BATCH * DOF
}

// ws layout (floats): [0..TPAD) = A_t, [TPAD..2*TPAD) = B_t,
//                     [(2+n)*TPAD + t] = H_t[n]
__global__ __launch_bounds__(512)
void dmp_precompute(const float* __restrict__ c, const float* __restrict__ s2,
                    float* __restrict__ ws) {
  __shared__ float g[TS][NB];
  __shared__ float cS[NB], vS[NB];
  const int tid = threadIdx.x;
  if (tid < NB) { cS[tid] = c[tid]; vS[tid] = s2[tid]; }
  __syncthreads();
  const float q = 1.0f - AX / TAU * DT;   // cx multiplier per step
  for (int i = tid; i < TS; i += 512) {
    float cx = powf(q, (float)(i + 1));   // cx updated BEFORE use in ref
    float p[NB]; float sum = 0.f;
    #pragma unroll
    for (int n = 0; n < NB; ++n) {
      float d = cx - cS[n];
      p[n] = expf(-0.5f * d * d / vS[n]);
      sum += p[n];
    }
    float m = cx / sum;
    #pragma unroll
    for (int n = 0; n < NB; ++n) g[i][n] = p[n] * m;
  }
  __syncthreads();
  // 27 independent linear-response recurrences (lanes 0..26)
  if (tid < NB + 2) {
    float y, gl;
    if (tid == 0)      { y = 1.f; gl = 0.f; }   // response to y0
    else if (tid == 1) { y = 0.f; gl = 1.f; }   // response to goal
    else               { y = 0.f; gl = 0.f; }   // response to unit w_n
    float z = 0.f;
    const int nn = (tid >= 2) ? (tid - 2) : 0;
    float* dst = ws + tid * TPAD;
    for (int t = 0; t < TS; ++t) {
      float fx = (tid >= 2) ? g[t][nn] : 0.f;
      float dy = z / TAU;
      float dz = (AZ * (BZ * (gl - y) - z) + fx) / TAU;
      y += dy * DT;
      z += dz * DT;
      dst[t] = y;
    }
  }
}

// Wave = 64 same-dof rows x ALL 301 t (5 t per lane: t = lane + 64c).
// h-tables for the wave's dof (a[5],b[5],h[5][25] = 135 VGPR) resident.
// Row broadcast via LDS: block stages its 256 rows (28 KB, stride 28 for
// 16B alignment) with coalesced VMEM once; row loop reads 7 uniform-addr
// ds_read_b128 broadcasts (R9 failure: SMEM K$ streams 14MB with ~no
// outstanding-miss capacity -> serialized line fills, ~2x stall).
// Stores: 5 x 256B coalesced per row (masked tail chunk).
__global__ __launch_bounds__(256, 2)
void dmp_main(const float* __restrict__ x, const float* __restrict__ scale,
              const float* __restrict__ ws, float* __restrict__ out) {
  __shared__ float sh[256 * 28];
  const int tid  = threadIdx.x;
  const int w    = tid >> 6;
  const int lane = tid & 63;
  const int dof  = w & 1;

  // ---- stage 256 rows x 27 floats -> LDS (stride 28), coalesced ----
  {
    const float* __restrict__ xsrc = x + (size_t)blockIdx.x * (256 * 27);
    #pragma unroll
    for (int it = 0; it < 27; ++it) {
      const int e = it * 256 + tid;
      const int r = e / 27;
      const int k = e - r * 27;
      sh[r * 28 + k] = xsrc[e];
    }
  }

  // ---- per-lane t-tables for 5 chunks ----
  float a0, a1, a2, a3, a4, b0, b1, b2, b3, b4;
  float h0[NB], h1[NB], h2[NB], h3[NB], h4[NB];
  {
    const int t0 = lane, t1 = lane + 64, t2 = lane + 128, t3 = lane + 192;
    const int t4 = (lane + 256 < TS) ? (lane + 256) : (TS - 1);
    a0 = ws[t0]; a1 = ws[t1]; a2 = ws[t2]; a3 = ws[t3]; a4 = ws[t4];
    b0 = ws[TPAD + t0]; b1 = ws[TPAD + t1]; b2 = ws[TPAD + t2];
    b3 = ws[TPAD + t3]; b4 = ws[TPAD + t4];
    #pragma unroll
    for (int k = 0; k < NB; ++k) {
      const float sk = scale[dof * 27 + 2 + k];
      const float* hp = ws + (2 + k) * TPAD;
      h0[k] = hp[t0] * sk; h1[k] = hp[t1] * sk; h2[k] = hp[t2] * sk;
      h3[k] = hp[t3] * sk; h4[k] = hp[t4] * sk;
    }
  }
  float vs0 = scale[dof * 27], vs1 = scale[dof * 27 + 1];
  // pin tables resident (R4 lesson: allocator sinks loop-invariant loads)
  asm volatile("" : "+v"(a0), "+v"(a1), "+v"(a2), "+v"(a3), "+v"(a4));
  asm volatile("" : "+v"(b0), "+v"(b1), "+v"(b2), "+v"(b3), "+v"(b4));
  asm volatile("" : "+v"(vs0), "+v"(vs1));
  #pragma unroll
  for (int k = 0; k < NB; ++k) {
    asm volatile("" : "+v"(h0[k]), "+v"(h1[k]), "+v"(h2[k]), "+v"(h3[k]), "+v"(h4[k]));
  }

  __syncthreads();

  const bool tail  = (lane < TS - 256);     // 45 valid lanes in chunk 4
  const int  lrow0 = (w >> 1) * 128 + dof;  // this wave's first LDS row
  const size_t gbase = (size_t)blockIdx.x * 256 + lrow0;

  #pragma unroll 1
  for (int i = 0; i < 64; ++i) {
    const int lr = lrow0 + 2 * i;
    const float4* __restrict__ rp = (const float4*)(sh + lr * 28);
    const float4 q0 = rp[0], q1 = rp[1], q2 = rp[2], q3 = rp[3];
    const float4 q4 = rp[4], q5 = rp[5], q6 = rp[6];
    float xv[27];
    xv[0]=q0.x;  xv[1]=q0.y;  xv[2]=q0.z;  xv[3]=q0.w;
    xv[4]=q1.x;  xv[5]=q1.y;  xv[6]=q1.z;  xv[7]=q1.w;
    xv[8]=q2.x;  xv[9]=q2.y;  xv[10]=q2.z; xv[11]=q2.w;
    xv[12]=q3.x; xv[13]=q3.y; xv[14]=q3.z; xv[15]=q3.w;
    xv[16]=q4.x; xv[17]=q4.y; xv[18]=q4.z; xv[19]=q4.w;
    xv[20]=q5.x; xv[21]=q5.y; xv[22]=q5.z; xv[23]=q5.w;
    xv[24]=q6.x; xv[25]=q6.y; xv[26]=q6.z;

    const float y0s = xv[0] * vs0;
    const float gs  = xv[1] * vs1;
    const float dd  = gs - y0s;
    float dA0 = 0.f, dA1 = 0.f, dB0 = 0.f, dB1 = 0.f, dC0 = 0.f,
          dC1 = 0.f, dD0 = 0.f, dD1 = 0.f, dE0 = 0.f, dE1 = 0.f;
    #pragma unroll
    for (int k = 0; k < 24; k += 2) {
      const float xk  = xv[2 + k];
      const float xk1 = xv[3 + k];
      dA0 = fmaf(xk, h0[k], dA0); dA1 = fmaf(xk1, h0[k + 1], dA1);
      dB0 = fmaf(xk, h1[k], dB0); dB1 = fmaf(xk1, h1[k + 1], dB1);
      dC0 = fmaf(xk, h2[k], dC0); dC1 = fmaf(xk1, h2[k + 1], dC1);
      dD0 = fmaf(xk, h3[k], dD0); dD1 = fmaf(xk1, h3[k + 1], dD1);
      dE0 = fmaf(xk, h4[k], dE0); dE1 = fmaf(xk1, h4[k + 1], dE1);
    }
    const float x24 = xv[26];
    dA0 = fmaf(x24, h0[24], dA0); dB0 = fmaf(x24, h1[24], dB0);
    dC0 = fmaf(x24, h2[24], dC0); dD0 = fmaf(x24, h3[24], dD0);
    dE0 = fmaf(x24, h4[24], dE0);

    float* __restrict__ orow = out + (gbase + 2 * (size_t)i) * TS;
    orow[lane]       = fmaf(a0, y0s, fmaf(b0, gs, dd * (dA0 + dA1)));
    orow[lane + 64]  = fmaf(a1, y0s, fmaf(b1, gs, dd * (dB0 + dB1)));
    orow[lane + 128] = fmaf(a2, y0s, fmaf(b2, gs, dd * (dC0 + dC1)));
    orow[lane + 192] = fmaf(a3, y0s, fmaf(b3, gs, dd * (dD0 + dD1)));
    if (tail)
      orow[lane + 256] = fmaf(a4, y0s, fmaf(b4, gs, dd * (dE0 + dE1)));
  }
}

extern "C" void kernel_launch(void* const* d_in, const int* in_sizes, int n_in,
                              void* d_out, int out_size, void* d_ws, size_t ws_size,
                              hipStream_t stream) {
  const float* x  = (const float*)d_in[0];
  const float* c  = (const float*)d_in[1];
  const float* s2 = (const float*)d_in[2];
  const float* sc = (const float*)d_in[3];
  float* ws  = (float*)d_ws;   // needs 27*304*4 = 32,832 bytes
  float* out = (float*)d_out;

  hipLaunchKernelGGL(dmp_precompute, dim3(1), dim3(512), 0, stream, c, s2, ws);
  hipLaunchKernelGGL(dmp_main, dim3(ROWS / 256), dim3(256), 0, stream,
                     x, sc, ws, out);
}